// Round 1
// baseline (265.347 us; speedup 1.0000x reference)
//
#include <hip/hip_runtime.h>

// Gabor layer: out[i,o] = sin(x[i]·W[o] + b[o]) * exp(-0.5*||x[i]-mu[o]||^2 * gamma[o])
// B=262144 rows, O=256 outputs, D=2.
// HBM-write-bound: 256 MiB out => ~43 us floor at 6.3 TB/s.

#define NROWS 262144
#define NOUT  256

__global__ __launch_bounds__(256, 4)
void gabor_kernel(const float* __restrict__ x,
                  const float* __restrict__ W,
                  const float* __restrict__ b,
                  const float* __restrict__ mu,
                  const float* __restrict__ gamma,
                  float* __restrict__ out,
                  int rows_per_block)
{
    const int tid  = threadIdx.x;
    const int oq   = (tid & 63) * 4;   // this thread's 4 consecutive outputs
    const int rsub = tid >> 6;         // row offset 0..3 within a chunk

    // Hoist per-output constants into registers (amortized over rows_per_block rows).
    float W0[4], W1[4], bb[4], mu0[4], mu1[4], ng[4];
#pragma unroll
    for (int j = 0; j < 4; ++j) {
        const int o = oq + j;
        W0[j]  = W[o * 2 + 0];
        W1[j]  = W[o * 2 + 1];
        bb[j]  = b[o];
        mu0[j] = mu[o * 2 + 0];
        mu1[j] = mu[o * 2 + 1];
        ng[j]  = -0.5f * gamma[o];
    }

    const int row_base = blockIdx.x * rows_per_block;
#pragma unroll 2
    for (int r = rsub; r < rows_per_block; r += 4) {
        const int i = row_base + r;
        const float2 xv = *reinterpret_cast<const float2*>(x + (size_t)i * 2);

        float4 res;
        float* rp = &res.x;
#pragma unroll
        for (int j = 0; j < 4; ++j) {
            const float lin = __fmaf_rn(xv.x, W0[j], __fmaf_rn(xv.y, W1[j], bb[j]));
            const float dx  = xv.x - mu0[j];
            const float dy  = xv.y - mu1[j];
            const float d2  = __fmaf_rn(dy, dy, dx * dx);
            rp[j] = __sinf(lin) * __expf(d2 * ng[j]);
        }
        // Wave of 64 lanes writes 64 contiguous float4 = 1 KiB per row.
        *reinterpret_cast<float4*>(out + (size_t)i * NOUT + oq) = res;
    }
}

extern "C" void kernel_launch(void* const* d_in, const int* in_sizes, int n_in,
                              void* d_out, int out_size, void* d_ws, size_t ws_size,
                              hipStream_t stream)
{
    const float* x     = (const float*)d_in[0];  // (B, 2)
    const float* W     = (const float*)d_in[1];  // (O, 2)
    const float* b     = (const float*)d_in[2];  // (O,)
    const float* mu    = (const float*)d_in[3];  // (1, O, 2)
    const float* gamma = (const float*)d_in[4];  // (O,)
    float* out = (float*)d_out;                  // (B, O)

    const int rows_per_block = 64;
    const int grid = NROWS / rows_per_block;     // 4096 blocks, 256 thr each
    gabor_kernel<<<grid, 256, 0, stream>>>(x, W, b, mu, gamma, out, rows_per_block);
}